// Round 9
// baseline (216.134 us; speedup 1.0000x reference)
//
#include <hip/hip_runtime.h>

#define Hn 128
#define Ln 2048
#define NBn 64
#define K 64          // chunk length
#define G 32          // chunks: G*K == Ln
#define PITCH 65      // 64+1: bank (n+k)%32 per phase -> conflict-free b32
                      // (measured 0 conflicts R1/R7; PITCH 68+b128 was 8-way)
#define POISON 0xAAAAAAAAu   // harness pre-poisons ws with 0xAA bytes

// w-space: w = 2*C*z follows the same diagonal recurrence with input
// coefficient 2*C*B;  y_t = sum_n Re(w_n) + D*u_t;  final z = w/(2C).
// ws layout: Sum[(h*G+g)*NBn+n] float4 {a_re,a_im,b_re,b_im} (4 MB),
//            Sin[...] float2 (2 MB), cnt[Hn] uint (512 B)

// ---------------------------------------------------------------------------
// Kernel A: phase-1 local w-space scan per (h,chunk)  +  last-block-per-head
// runs the serial combine (old phase2) exactly once. Block = ONE wave, so a
// wave-wide __threadfence() after the summary store is a full release; lane 0
// then bumps the per-head counter (device scope).
// ---------------------------------------------------------------------------
__global__ __launch_bounds__(64) void phaseA(
    const float* __restrict__ u,
    const float* __restrict__ x_re, const float* __restrict__ x_im,
    const float* __restrict__ Lre,  const float* __restrict__ Lim,
    const float* __restrict__ Bre,  const float* __restrict__ Bim,
    const float* __restrict__ Cre,  const float* __restrict__ Cim,
    const float* __restrict__ Dv,   const int* __restrict__ dflag,
    float* __restrict__ out,
    float4* __restrict__ Sum, float2* __restrict__ Sin,
    unsigned int* __restrict__ cnt)
{
    __shared__ float g_s[K * PITCH];
    __shared__ float u_s[K];

    const int g = blockIdx.x, h = blockIdx.y, n = threadIdx.x;
    const int hn = h * NBn + n;
    const int l0 = g * K;

    const float lre = Lre[hn], lim = Lim[hn];
    const float br  = Bre[hn], bi  = Bim[hn];
    const float cr  = Cre[hn], ci  = Cim[hn];
    const float Dh  = Dv[h];
    const float cbr2 = 2.f * (cr * br - ci * bi);   // 2*C*B
    const float cbi2 = 2.f * (cr * bi + ci * br);

    u_s[n] = u[h * Ln + l0 + n];
    const unsigned long long m = __ballot(dflag[l0 + n] != 0);
    __syncthreads();

    float wr = 0.f, wi = 0.f;
    if (m == 0ull) {                 // reset-free chunk (~53%)
        #pragma unroll
        for (int k = 0; k < K; ++k) {
            const float uk = u_s[k];               // LDS broadcast (DS pipe)
            const float nr = fmaf(lre, wr, fmaf(-lim, wi, cbr2 * uk));
            const float ni = fmaf(lre, wi, fmaf( lim, wr, cbi2 * uk));
            wr = nr; wi = ni;
            g_s[k * PITCH + n] = wr;               // only Re needed for y
        }
    } else {
        #pragma unroll
        for (int k = 0; k < K; ++k) {
            const bool  rs  = (m >> k) & 1ull;     // wave-uniform select
            const float lrk = rs ? 0.f : lre;
            const float lik = rs ? 0.f : lim;
            const float uk  = u_s[k];
            const float nr = fmaf(lrk, wr, fmaf(-lik, wi, cbr2 * uk));
            const float ni = fmaf(lrk, wi, fmaf( lik, wr, cbi2 * uk));
            wr = nr; wi = ni;
            g_s[k * PITCH + n] = wr;
        }
    }
    __syncthreads();

    // lane t sums row t (timestep l0+t): conflict-free b32 at PITCH 65
    {
        const float* row = g_s + n * PITCH;
        float a0 = 0.f, a1 = 0.f, a2 = 0.f, a3 = 0.f;
        #pragma unroll
        for (int k = 0; k < NBn; k += 4) {
            a0 += row[k + 0]; a1 += row[k + 1];
            a2 += row[k + 2]; a3 += row[k + 3];
        }
        out[h * Ln + l0 + n] = (a0 + a1) + (a2 + a3) + Dh * u_s[n];
    }

    // chunk summary: Lam^64 via 6 squarings, zeroed if any reset in chunk
    float pr = lre, pi = lim;
    #pragma unroll
    for (int it = 0; it < 6; ++it) {
        const float sr2 = pr * pr - pi * pi;
        const float si2 = 2.f * pr * pi;
        pr = sr2; pi = si2;
    }
    if (m) { pr = 0.f; pi = 0.f; }
    Sum[(h * G + g) * NBn + n] = make_float4(pr, pi, wr, wi);

    // ---- completion count; last block of this head runs the combine ----
    __threadfence();                              // release (whole wave)
    unsigned int old = 0;
    if (n == 0) old = atomicAdd(&cnt[h], 1u);
    old = __builtin_amdgcn_readfirstlane(old);
    if (old != POISON + (G - 1)) return;          // not last: done
    __threadfence();                              // acquire

    // ---- serial combine over the head's 32 summaries (old phase2) ----
    const float x0r = x_re[hn], x0i = x_im[hn];
    float sre = 2.f * (cr * x0r - ci * x0i);      // w-space initial state
    float sim = 2.f * (cr * x0i + ci * x0r);
    const float4* base = Sum + h * G * NBn + n;
    float2* sbase = Sin + h * G * NBn + n;
    #pragma unroll
    for (int j = 0; j < G; ++j) {
        const float4 s = base[j * NBn];
        sbase[j * NBn] = make_float2(sre, sim);
        const float nr = fmaf(s.x, sre, fmaf(-s.y, sim, s.z));
        const float ni = fmaf(s.x, sim, fmaf( s.y, sre, s.w));
        sre = nr; sim = ni;
    }
    const float c2r = 2.f * cr, c2i = 2.f * ci;   // z = w/(2C)
    const float inv = 1.f / (c2r * c2r + c2i * c2i);
    float* xlast = out + Hn * Ln;
    xlast[2 * hn + 0] = (sre * c2r + sim * c2i) * inv;
    xlast[2 * hn + 1] = (sim * c2r - sre * c2i) * inv;
}

// ---------------------------------------------------------------------------
// Kernel B: per-(h,chunk) correction  y[l0+k] += sum_n Re(Lam_n^{k+1} w_in_n)
// masked from the first reset onward; two interleaved Lam^2 chains.
// ---------------------------------------------------------------------------
__global__ __launch_bounds__(64) void phaseB_fixup(
    const float* __restrict__ Lre, const float* __restrict__ Lim,
    const int* __restrict__ dflag,
    const float2* __restrict__ Sin,
    float* __restrict__ out)
{
    __shared__ float g_s[K * PITCH];

    const int g = blockIdx.x, h = blockIdx.y, n = threadIdx.x;
    const int hn = h * NBn + n;
    const int l0 = g * K;

    const float2 s = Sin[(h * G + g) * NBn + n];   // w_in
    const float lre = Lre[hn], lim = Lim[hn];

    const unsigned long long bal = __ballot(dflag[l0 + n] != 0);
    const int kr = bal ? (__ffsll((long long)bal) - 1) : K;

    const float l2r = lre * lre - lim * lim;       // Lam^2
    const float l2i = 2.f * lre * lim;

    float tAr = fmaf(lre, s.x, -lim * s.y);        // k=0: w_in*Lam
    float tAi = fmaf(lre, s.y,  lim * s.x);
    float tBr = fmaf(l2r, s.x, -l2i * s.y);        // k=1: w_in*Lam^2
    float tBi = fmaf(l2r, s.y,  l2i * s.x);
    g_s[0 * PITCH + n] = tAr;
    g_s[1 * PITCH + n] = tBr;
    #pragma unroll
    for (int k = 2; k < K; k += 2) {
        const float nAr = fmaf(l2r, tAr, -l2i * tAi);
        const float nAi = fmaf(l2r, tAi,  l2i * tAr);
        tAr = nAr; tAi = nAi;
        g_s[k * PITCH + n] = tAr;
        const float nBr = fmaf(l2r, tBr, -l2i * tBi);
        const float nBi = fmaf(l2r, tBi,  l2i * tBr);
        tBr = nBr; tBi = nBi;
        g_s[(k + 1) * PITCH + n] = tBr;
    }
    __syncthreads();

    const float* row = g_s + n * PITCH;
    float a0 = 0.f, a1 = 0.f, a2 = 0.f, a3 = 0.f;
    #pragma unroll
    for (int k = 0; k < NBn; k += 4) {
        a0 += row[k + 0]; a1 += row[k + 1];
        a2 += row[k + 2]; a3 += row[k + 3];
    }
    if (n < kr)
        out[h * Ln + l0 + n] += (a0 + a1) + (a2 + a3);
}

extern "C" void kernel_launch(void* const* d_in, const int* in_sizes, int n_in,
                              void* d_out, int out_size, void* d_ws, size_t ws_size,
                              hipStream_t stream) {
    const float* u    = (const float*)d_in[0];
    const float* x_re = (const float*)d_in[1];
    const float* x_im = (const float*)d_in[2];
    const float* Lre  = (const float*)d_in[3];
    const float* Lim  = (const float*)d_in[4];
    const float* Bre  = (const float*)d_in[5];
    const float* Bim  = (const float*)d_in[6];
    const float* Cre  = (const float*)d_in[7];
    const float* Cim  = (const float*)d_in[8];
    const float* Dv   = (const float*)d_in[9];
    const int*   dfl  = (const int*)d_in[10];
    float* out = (float*)d_out;

    const int HGN = Hn * G * NBn;              // 262144 entries
    float4*       Sum = (float4*)d_ws;         // 4 MB
    float2*       Sin = (float2*)(Sum + HGN);  // 2 MB
    unsigned int* cnt = (unsigned int*)(Sin + HGN);  // 128 uints,
    // pre-poisoned to 0xAAAAAAAA each launch -> "last" == POISON + G-1.

    dim3 grid(G, Hn);
    phaseA<<<grid, 64, 0, stream>>>(u, x_re, x_im, Lre, Lim, Bre, Bim,
                                    Cre, Cim, Dv, dfl, out, Sum, Sin, cnt);
    phaseB_fixup<<<grid, 64, 0, stream>>>(Lre, Lim, dfl, Sin, out);
}

// Round 10
// 96.614 us; speedup vs baseline: 2.2371x; 2.2371x over previous
//
#include <hip/hip_runtime.h>

#define Hn 128
#define Ln 2048
#define NBn 64
#define K 64          // chunk length
#define G 32          // chunks: G*K == Ln
#define PITCH 65      // 64+1: bank (n+k)%32 per phase -> conflict-free b32
                      // (measured 0 conflicts R1/R7; strided b128 was 8-way R6)

// w-space: w = 2*C*z follows the same diagonal recurrence with input
// coefficient 2*C*B;  y_t = sum_n Re(w_n) + D*u_t;  final z = w/(2C).
// ws layout: Sum[(h*G+g)*NBn+n] float4 {a_re,a_im,b_re,b_im} (4 MB).
// RULE (R6/R9): no cross-block fences/spins/atomics — kernel boundary only.

// ---------------------------------------------------------------------------
// Kernel A: per-(h,chunk) local w-space scan (s_in = 0).
//   y_local (incl. D*u) -> out;  chunk summary float4 -> Sum.
// ---------------------------------------------------------------------------
__global__ __launch_bounds__(64) void phaseA_local(
    const float* __restrict__ u,
    const float* __restrict__ Lre,  const float* __restrict__ Lim,
    const float* __restrict__ Bre,  const float* __restrict__ Bim,
    const float* __restrict__ Cre,  const float* __restrict__ Cim,
    const float* __restrict__ Dv,   const int* __restrict__ dflag,
    float* __restrict__ out,
    float4* __restrict__ Sum)
{
    __shared__ float g_s[K * PITCH];
    __shared__ float u_s[K];

    const int g = blockIdx.x, h = blockIdx.y, n = threadIdx.x;
    const int hn = h * NBn + n;
    const int l0 = g * K;

    const float lre = Lre[hn], lim = Lim[hn];
    const float br  = Bre[hn], bi  = Bim[hn];
    const float cr  = Cre[hn], ci  = Cim[hn];
    const float Dh  = Dv[h];
    const float cbr2 = 2.f * (cr * br - ci * bi);   // 2*C*B
    const float cbi2 = 2.f * (cr * bi + ci * br);

    u_s[n] = u[h * Ln + l0 + n];
    const unsigned long long m = __ballot(dflag[l0 + n] != 0);
    __syncthreads();

    float wr = 0.f, wi = 0.f;
    if (m == 0ull) {                 // reset-free chunk (~53%)
        #pragma unroll
        for (int k = 0; k < K; ++k) {
            const float uk = u_s[k];               // LDS broadcast (DS pipe)
            const float nr = fmaf(lre, wr, fmaf(-lim, wi, cbr2 * uk));
            const float ni = fmaf(lre, wi, fmaf( lim, wr, cbi2 * uk));
            wr = nr; wi = ni;
            g_s[k * PITCH + n] = wr;               // only Re needed for y
        }
    } else {
        #pragma unroll
        for (int k = 0; k < K; ++k) {
            const bool  rs  = (m >> k) & 1ull;     // wave-uniform select
            const float lrk = rs ? 0.f : lre;
            const float lik = rs ? 0.f : lim;
            const float uk  = u_s[k];
            const float nr = fmaf(lrk, wr, fmaf(-lik, wi, cbr2 * uk));
            const float ni = fmaf(lrk, wi, fmaf( lik, wr, cbi2 * uk));
            wr = nr; wi = ni;
            g_s[k * PITCH + n] = wr;
        }
    }
    __syncthreads();

    // lane t sums row t (timestep l0+t): conflict-free b32 at PITCH 65
    const float* row = g_s + n * PITCH;
    float a0 = 0.f, a1 = 0.f, a2 = 0.f, a3 = 0.f;
    #pragma unroll
    for (int k = 0; k < NBn; k += 4) {
        a0 += row[k + 0]; a1 += row[k + 1];
        a2 += row[k + 2]; a3 += row[k + 3];
    }
    out[h * Ln + l0 + n] = (a0 + a1) + (a2 + a3) + Dh * u_s[n];

    // chunk summary: Lam^64 via 6 squarings, zeroed if any reset in chunk
    float pr = lre, pi = lim;
    #pragma unroll
    for (int it = 0; it < 6; ++it) {
        const float sr2 = pr * pr - pi * pi;
        const float si2 = 2.f * pr * pi;
        pr = sr2; pi = si2;
    }
    if (m) { pr = 0.f; pi = 0.f; }
    Sum[(h * G + g) * NBn + n] = make_float4(pr, pi, wr, wi);
}

// ---------------------------------------------------------------------------
// Kernel B: per-HEAD combine + correction. Block = head (4 waves).
// Summaries staged to LDS once (4 MB total global traffic, same as the old
// phase2). Wave w owns chunks j == w (mod 4); every wave advances the
// w-state through all 32 LDS summaries (this IS the prefix), and at its own
// chunks runs the correction  y[l0+k] += sum_n Re(Lam_n^{k+1} w_in_n),
// masked from the first reset onward. Wave 0 emits the final z = w/(2C).
// ---------------------------------------------------------------------------
__global__ __launch_bounds__(256) void phaseB_head(
    const float* __restrict__ x_re, const float* __restrict__ x_im,
    const float* __restrict__ Lre,  const float* __restrict__ Lim,
    const float* __restrict__ Cre,  const float* __restrict__ Cim,
    const int* __restrict__ dflag,
    const float4* __restrict__ Sum,
    float* __restrict__ out)
{
    __shared__ float4 S_s[G * NBn];        // 32 KB summaries
    __shared__ float  g_s[4][K * PITCH];   // 66.6 KB transpose buffers

    const int h = blockIdx.x, tid = threadIdx.x;
    const int w = tid >> 6, n = tid & 63;
    const int hn = h * NBn + n;

    // stage summaries: 2048 float4, 256 threads -> 8 coalesced b128 each
    const float4* src = Sum + h * G * NBn;
    #pragma unroll
    for (int i = 0; i < 8; ++i)
        S_s[tid + 256 * i] = src[tid + 256 * i];

    // prefetch this wave's 8 reset masks (off the serial chain)
    unsigned long long mk[8];
    #pragma unroll
    for (int jj = 0; jj < 8; ++jj)
        mk[jj] = __ballot(dflag[(4 * jj + w) * K + n] != 0);

    const float lre = Lre[hn], lim = Lim[hn];
    const float cr  = Cre[hn], ci  = Cim[hn];
    const float x0r = x_re[hn], x0i = x_im[hn];
    float sre = 2.f * (cr * x0r - ci * x0i);    // w-space initial state
    float sim = 2.f * (cr * x0i + ci * x0r);
    const float l2r = lre * lre - lim * lim;    // Lam^2
    const float l2i = 2.f * lre * lim;

    __syncthreads();

    float* gbuf = g_s[w];
    #pragma unroll
    for (int j = 0; j < G; ++j) {
        if ((j & 3) == w) {
            // ---- correction for chunk j with w_in = (sre,sim) ----
            const int jj = j >> 2;
            const int l0 = j * K;
            const unsigned long long mm = mk[jj];
            const int kr = mm ? (__ffsll((long long)mm) - 1) : K;

            float tAr = fmaf(lre, sre, -lim * sim);   // k=0: w_in*Lam
            float tAi = fmaf(lre, sim,  lim * sre);
            float tBr = fmaf(l2r, sre, -l2i * sim);   // k=1: w_in*Lam^2
            float tBi = fmaf(l2r, sim,  l2i * sre);
            gbuf[0 * PITCH + n] = tAr;
            gbuf[1 * PITCH + n] = tBr;
            #pragma unroll
            for (int k = 2; k < K; k += 2) {
                const float nAr = fmaf(l2r, tAr, -l2i * tAi);
                const float nAi = fmaf(l2r, tAi,  l2i * tAr);
                tAr = nAr; tAi = nAi;
                gbuf[k * PITCH + n] = tAr;
                const float nBr = fmaf(l2r, tBr, -l2i * tBi);
                const float nBi = fmaf(l2r, tBi,  l2i * tBr);
                tBr = nBr; tBi = nBi;
                gbuf[(k + 1) * PITCH + n] = tBr;
            }
            // same-wave DS is in-order: no barrier (wave-private buffer)
            const float* row = gbuf + n * PITCH;
            float a0 = 0.f, a1 = 0.f, a2 = 0.f, a3 = 0.f;
            #pragma unroll
            for (int k = 0; k < NBn; k += 4) {
                a0 += row[k + 0]; a1 += row[k + 1];
                a2 += row[k + 2]; a3 += row[k + 3];
            }
            if (n < kr)
                out[h * Ln + l0 + n] += (a0 + a1) + (a2 + a3);
        }
        // ---- advance through chunk j (identical fmaf seq to old phase2) ----
        const float4 s = S_s[j * NBn + n];
        const float nr = fmaf(s.x, sre, fmaf(-s.y, sim, s.z));
        const float ni = fmaf(s.x, sim, fmaf( s.y, sre, s.w));
        sre = nr; sim = ni;
    }

    if (w == 0) {                               // final state z = w/(2C)
        const float c2r = 2.f * cr, c2i = 2.f * ci;
        const float inv = 1.f / (c2r * c2r + c2i * c2i);
        float* xlast = out + Hn * Ln;
        xlast[2 * hn + 0] = (sre * c2r + sim * c2i) * inv;
        xlast[2 * hn + 1] = (sim * c2r - sre * c2i) * inv;
    }
}

extern "C" void kernel_launch(void* const* d_in, const int* in_sizes, int n_in,
                              void* d_out, int out_size, void* d_ws, size_t ws_size,
                              hipStream_t stream) {
    const float* u    = (const float*)d_in[0];
    const float* x_re = (const float*)d_in[1];
    const float* x_im = (const float*)d_in[2];
    const float* Lre  = (const float*)d_in[3];
    const float* Lim  = (const float*)d_in[4];
    const float* Bre  = (const float*)d_in[5];
    const float* Bim  = (const float*)d_in[6];
    const float* Cre  = (const float*)d_in[7];
    const float* Cim  = (const float*)d_in[8];
    const float* Dv   = (const float*)d_in[9];
    const int*   dfl  = (const int*)d_in[10];
    float* out = (float*)d_out;

    float4* Sum = (float4*)d_ws;           // 4 MB

    dim3 gridA(G, Hn);
    phaseA_local<<<gridA, 64, 0, stream>>>(u, Lre, Lim, Bre, Bim, Cre, Cim,
                                           Dv, dfl, out, Sum);
    phaseB_head<<<Hn, 256, 0, stream>>>(x_re, x_im, Lre, Lim, Cre, Cim,
                                        dfl, Sum, out);
}

// Round 11
// 89.074 us; speedup vs baseline: 2.4265x; 1.0846x over previous
//
#include <hip/hip_runtime.h>

#define Hn 128
#define Ln 2048
#define NBn 64
#define K 64          // chunk length
#define G 32          // chunks: G*K == Ln
#define PITCH 65      // 64+1: bank (n+k)%32 per phase -> conflict-free b32
                      // (measured 0 conflicts R1/R7; strided b128 was 8-way R6)

// w-space: w = 2*C*z follows the same diagonal recurrence with input
// coefficient 2*C*B;  y_t = sum_n Re(w_n) + D*u_t;  final z = w/(2C).
// ws: Sum[(h*G+g)*NBn+n] float4 {a_re,a_im,b_re,b_im} (4 MB),
//     Sin[...] float2 {w_in_re, w_in_im} (2 MB).
// Session rules (measured): work stays at (G,Hn) 4096-block spread; no
// cross-block fences/spins/atomics (R6/R9); no redundant prefix (R3/R8);
// no per-head concentration (R5/R10).

// ---------------------------------------------------------------------------
// K1: summary-only w-space chunk scan (s_in = 0). No transpose, no reduce,
// no y write — minimal critical path into K2.
// ---------------------------------------------------------------------------
__global__ __launch_bounds__(64) void k1_summary(
    const float* __restrict__ u,
    const float* __restrict__ Lre,  const float* __restrict__ Lim,
    const float* __restrict__ Bre,  const float* __restrict__ Bim,
    const float* __restrict__ Cre,  const float* __restrict__ Cim,
    const int* __restrict__ dflag,
    float4* __restrict__ Sum)
{
    __shared__ float u_s[K];

    const int g = blockIdx.x, h = blockIdx.y, n = threadIdx.x;
    const int hn = h * NBn + n;
    const int l0 = g * K;

    const float lre = Lre[hn], lim = Lim[hn];
    const float br  = Bre[hn], bi  = Bim[hn];
    const float cr  = Cre[hn], ci  = Cim[hn];
    const float cbr2 = 2.f * (cr * br - ci * bi);   // 2*C*B
    const float cbi2 = 2.f * (cr * bi + ci * br);

    u_s[n] = u[h * Ln + l0 + n];
    const unsigned long long m = __ballot(dflag[l0 + n] != 0);
    __syncthreads();

    float wr = 0.f, wi = 0.f;
    if (m == 0ull) {                 // reset-free chunk (~53%)
        #pragma unroll
        for (int k = 0; k < K; ++k) {
            const float uk = u_s[k];               // LDS broadcast
            const float nr = fmaf(lre, wr, fmaf(-lim, wi, cbr2 * uk));
            const float ni = fmaf(lre, wi, fmaf( lim, wr, cbi2 * uk));
            wr = nr; wi = ni;
        }
    } else {
        #pragma unroll
        for (int k = 0; k < K; ++k) {
            const bool  rs  = (m >> k) & 1ull;     // wave-uniform select
            const float lrk = rs ? 0.f : lre;
            const float lik = rs ? 0.f : lim;
            const float uk  = u_s[k];
            const float nr = fmaf(lrk, wr, fmaf(-lik, wi, cbr2 * uk));
            const float ni = fmaf(lrk, wi, fmaf( lik, wr, cbi2 * uk));
            wr = nr; wi = ni;
        }
    }

    // A = Lam^64 (6 squarings), zeroed if any reset in chunk
    float pr = lre, pi = lim;
    #pragma unroll
    for (int it = 0; it < 6; ++it) {
        const float sr2 = pr * pr - pi * pi;
        const float si2 = 2.f * pr * pi;
        pr = sr2; pi = si2;
    }
    if (m) { pr = 0.f; pi = 0.f; }
    Sum[(h * G + g) * NBn + n] = make_float4(pr, pi, wr, wi);
}

// ---------------------------------------------------------------------------
// K2: per-head serial combine in w-space (one dwordx4 per chunk, fully
// unrolled so loads pipeline ahead of the FMA chain); writes each chunk's
// incoming w-state to Sin; final z = w/(2C) -> out.
// ---------------------------------------------------------------------------
__global__ __launch_bounds__(64) void k2_combine(
    const float* __restrict__ x_re, const float* __restrict__ x_im,
    const float* __restrict__ Cre,  const float* __restrict__ Cim,
    const float4* __restrict__ Sum,
    float2* __restrict__ Sin,
    float* __restrict__ out)
{
    const int h = blockIdx.x, n = threadIdx.x;
    const int hn = h * NBn + n;
    const float cr = Cre[hn], ci = Cim[hn];
    const float x0r = x_re[hn], x0i = x_im[hn];
    float sre = 2.f * (cr * x0r - ci * x0i);    // w-space initial state
    float sim = 2.f * (cr * x0i + ci * x0r);
    #pragma unroll
    for (int g = 0; g < G; ++g) {
        const int idx = (h * G + g) * NBn + n;
        const float4 s = Sum[idx];
        Sin[idx] = make_float2(sre, sim);
        const float nr = fmaf(s.x, sre, fmaf(-s.y, sim, s.z));
        const float ni = fmaf(s.x, sim, fmaf( s.y, sre, s.w));
        sre = nr; sim = ni;
    }
    const float c2r = 2.f * cr, c2i = 2.f * ci; // z = w/(2C)
    const float inv = 1.f / (c2r * c2r + c2i * c2i);
    float* xlast = out + Hn * Ln;
    xlast[2 * hn + 0] = (sre * c2r + sim * c2i) * inv;
    xlast[2 * hn + 1] = (sim * c2r - sre * c2i) * inv;
}

// ---------------------------------------------------------------------------
// K3: full re-scan from the true incoming state (exact reference recurrence),
// transpose-reduce at PITCH 65, single coalesced y store (no RMW).
// ---------------------------------------------------------------------------
__global__ __launch_bounds__(64) void k3_rescan(
    const float* __restrict__ u,
    const float* __restrict__ Lre,  const float* __restrict__ Lim,
    const float* __restrict__ Bre,  const float* __restrict__ Bim,
    const float* __restrict__ Cre,  const float* __restrict__ Cim,
    const float* __restrict__ Dv,   const int* __restrict__ dflag,
    const float2* __restrict__ Sin,
    float* __restrict__ out)
{
    __shared__ float g_s[K * PITCH];
    __shared__ float u_s[K];

    const int g = blockIdx.x, h = blockIdx.y, n = threadIdx.x;
    const int hn = h * NBn + n;
    const int l0 = g * K;

    const float lre = Lre[hn], lim = Lim[hn];
    const float br  = Bre[hn], bi  = Bim[hn];
    const float cr  = Cre[hn], ci  = Cim[hn];
    const float Dh  = Dv[h];
    const float cbr2 = 2.f * (cr * br - ci * bi);   // 2*C*B
    const float cbi2 = 2.f * (cr * bi + ci * br);

    const float2 win = Sin[(h * G + g) * NBn + n];  // true incoming w
    const float ul = u[h * Ln + l0 + n];
    u_s[n] = ul;
    const unsigned long long m = __ballot(dflag[l0 + n] != 0);
    __syncthreads();

    float wr = win.x, wi = win.y;
    if (m == 0ull) {
        #pragma unroll
        for (int k = 0; k < K; ++k) {
            const float uk = u_s[k];
            const float nr = fmaf(lre, wr, fmaf(-lim, wi, cbr2 * uk));
            const float ni = fmaf(lre, wi, fmaf( lim, wr, cbi2 * uk));
            wr = nr; wi = ni;
            g_s[k * PITCH + n] = wr;               // only Re needed for y
        }
    } else {
        #pragma unroll
        for (int k = 0; k < K; ++k) {
            const bool  rs  = (m >> k) & 1ull;
            const float lrk = rs ? 0.f : lre;
            const float lik = rs ? 0.f : lim;
            const float uk  = u_s[k];
            const float nr = fmaf(lrk, wr, fmaf(-lik, wi, cbr2 * uk));
            const float ni = fmaf(lrk, wi, fmaf( lik, wr, cbi2 * uk));
            wr = nr; wi = ni;
            g_s[k * PITCH + n] = wr;
        }
    }
    __syncthreads();

    // lane t sums row t (timestep l0+t): conflict-free b32 at PITCH 65
    const float* row = g_s + n * PITCH;
    float a0 = 0.f, a1 = 0.f, a2 = 0.f, a3 = 0.f;
    #pragma unroll
    for (int k = 0; k < NBn; k += 4) {
        a0 += row[k + 0]; a1 += row[k + 1];
        a2 += row[k + 2]; a3 += row[k + 3];
    }
    out[h * Ln + l0 + n] = (a0 + a1) + (a2 + a3) + Dh * ul;
}

extern "C" void kernel_launch(void* const* d_in, const int* in_sizes, int n_in,
                              void* d_out, int out_size, void* d_ws, size_t ws_size,
                              hipStream_t stream) {
    const float* u    = (const float*)d_in[0];
    const float* x_re = (const float*)d_in[1];
    const float* x_im = (const float*)d_in[2];
    const float* Lre  = (const float*)d_in[3];
    const float* Lim  = (const float*)d_in[4];
    const float* Bre  = (const float*)d_in[5];
    const float* Bim  = (const float*)d_in[6];
    const float* Cre  = (const float*)d_in[7];
    const float* Cim  = (const float*)d_in[8];
    const float* Dv   = (const float*)d_in[9];
    const int*   dfl  = (const int*)d_in[10];
    float* out = (float*)d_out;

    const int HGN = Hn * G * NBn;          // 262144 entries
    float4* Sum = (float4*)d_ws;           // 4 MB
    float2* Sin = (float2*)(Sum + HGN);    // 2 MB

    dim3 grid(G, Hn);
    k1_summary<<<grid, 64, 0, stream>>>(u, Lre, Lim, Bre, Bim, Cre, Cim,
                                        dfl, Sum);
    k2_combine<<<Hn, 64, 0, stream>>>(x_re, x_im, Cre, Cim, Sum, Sin, out);
    k3_rescan<<<grid, 64, 0, stream>>>(u, Lre, Lim, Bre, Bim, Cre, Cim,
                                       Dv, dfl, Sin, out);
}

// Round 12
// 89.019 us; speedup vs baseline: 2.4280x; 1.0006x over previous
//
#include <hip/hip_runtime.h>

#define Hn 128
#define Ln 2048
#define NBn 64
#define K 64          // chunk length
#define G 32          // chunks: G*K == Ln
#define PITCH 65      // 64+1: bank (n+k)%32 per phase -> conflict-free b32
                      // (measured 0 conflicts R1/R7; strided b128 was 8-way R6)

// w-space: w = 2*C*z follows the same diagonal recurrence with input
// coefficient 2*C*B;  y_t = sum_n Re(w_n) + D*u_t;  final z = w/(2C).
// ws: Sin[(h*G+g)*NBn+n] float2 {w_in_re, w_in_im} (2 MB).
// Session rules (measured): heavy work stays at (G,Hn) 4096-block spread;
// no cross-block fences/spins/atomics (R6/R9); no redundant prefix (R3/R8);
// no concentration of LDS-heavy work (R5/R10). This round concentrates ONLY
// the summary latency-chains (no per-step LDS) + the tiny combine.

// ---------------------------------------------------------------------------
// Kernel A: per-HEAD summary + combine. Block = head, 16 waves; wave w owns
// chunks 2w, 2w+1 (summary-only scans, s_in = 0, no per-step LDS). Summaries
// land in LDS; after one barrier, wave 0 runs the 32-step serial combine,
// writes each chunk's incoming w-state to Sin and the final z to out.
// ---------------------------------------------------------------------------
__global__ __launch_bounds__(1024) void kA_sum_combine(
    const float* __restrict__ u,
    const float* __restrict__ x_re, const float* __restrict__ x_im,
    const float* __restrict__ Lre,  const float* __restrict__ Lim,
    const float* __restrict__ Bre,  const float* __restrict__ Bim,
    const float* __restrict__ Cre,  const float* __restrict__ Cim,
    const int* __restrict__ dflag,
    float2* __restrict__ Sin,
    float* __restrict__ out)
{
    __shared__ float  u_s[Ln];         // 8 KB
    __shared__ float4 b_s[G][NBn];     // 32 KB: {A_re, A_im, b_re, b_im}

    const int h = blockIdx.x, tid = threadIdx.x;
    const int w = tid >> 6, n = tid & 63;
    const int hn = h * NBn + n;

    const float lre = Lre[hn], lim = Lim[hn];
    const float br  = Bre[hn], bi  = Bim[hn];
    const float cr  = Cre[hn], ci  = Cim[hn];
    const float cbr2 = 2.f * (cr * br - ci * bi);   // 2*C*B
    const float cbi2 = 2.f * (cr * bi + ci * br);

    // stage u: 2048 floats, 1024 threads, coalesced
    u_s[tid]        = u[h * Ln + tid];
    u_s[tid + 1024] = u[h * Ln + tid + 1024];

    // reset masks for my 2 chunks (off the serial chain)
    unsigned long long mk[2];
    #pragma unroll
    for (int jj = 0; jj < 2; ++jj)
        mk[jj] = __ballot(dflag[(2 * w + jj) * K + n] != 0);

    // Lam^64 via 6 squarings
    float l64r = lre, l64i = lim;
    #pragma unroll
    for (int it = 0; it < 6; ++it) {
        const float a  = l64r * l64r - l64i * l64i;
        const float b2 = 2.f * l64r * l64i;
        l64r = a; l64i = b2;
    }

    __syncthreads();

    #pragma unroll
    for (int jj = 0; jj < 2; ++jj) {
        const int j  = 2 * w + jj;
        const int l0 = j * K;
        const unsigned long long m = mk[jj];
        float wr = 0.f, wi = 0.f;
        if (m == 0ull) {                 // reset-free chunk (~53%)
            #pragma unroll
            for (int k = 0; k < K; ++k) {
                const float uk = u_s[l0 + k];       // LDS broadcast
                const float nr = fmaf(lre, wr, fmaf(-lim, wi, cbr2 * uk));
                const float ni = fmaf(lre, wi, fmaf( lim, wr, cbi2 * uk));
                wr = nr; wi = ni;
            }
        } else {
            #pragma unroll
            for (int k = 0; k < K; ++k) {
                const bool  rs  = (m >> k) & 1ull;  // wave-uniform select
                const float lrk = rs ? 0.f : lre;
                const float lik = rs ? 0.f : lim;
                const float uk  = u_s[l0 + k];
                const float nr = fmaf(lrk, wr, fmaf(-lik, wi, cbr2 * uk));
                const float ni = fmaf(lrk, wi, fmaf( lik, wr, cbi2 * uk));
                wr = nr; wi = ni;
            }
        }
        const float ar = m ? 0.f : l64r;
        const float ai = m ? 0.f : l64i;
        b_s[j][n] = make_float4(ar, ai, wr, wi);
    }
    __syncthreads();

    if (w == 0) {
        // serial combine (identical fmaf sequence to the proven k2_combine)
        const float x0r = x_re[hn], x0i = x_im[hn];
        float sre = 2.f * (cr * x0r - ci * x0i);
        float sim = 2.f * (cr * x0i + ci * x0r);
        float2* sbase = Sin + h * G * NBn + n;
        #pragma unroll
        for (int g = 0; g < G; ++g) {
            const float4 s = b_s[g][n];
            sbase[g * NBn] = make_float2(sre, sim);
            const float nr = fmaf(s.x, sre, fmaf(-s.y, sim, s.z));
            const float ni = fmaf(s.x, sim, fmaf( s.y, sre, s.w));
            sre = nr; sim = ni;
        }
        const float c2r = 2.f * cr, c2i = 2.f * ci;   // z = w/(2C)
        const float inv = 1.f / (c2r * c2r + c2i * c2i);
        float* xlast = out + Hn * Ln;
        xlast[2 * hn + 0] = (sre * c2r + sim * c2i) * inv;
        xlast[2 * hn + 1] = (sim * c2r - sre * c2i) * inv;
    }
}

// ---------------------------------------------------------------------------
// Kernel B: full re-scan from the true incoming state (exact reference
// recurrence), transpose-reduce at PITCH 65, single coalesced y store.
// Unchanged from R11's proven k3_rescan.
// ---------------------------------------------------------------------------
__global__ __launch_bounds__(64) void kB_rescan(
    const float* __restrict__ u,
    const float* __restrict__ Lre,  const float* __restrict__ Lim,
    const float* __restrict__ Bre,  const float* __restrict__ Bim,
    const float* __restrict__ Cre,  const float* __restrict__ Cim,
    const float* __restrict__ Dv,   const int* __restrict__ dflag,
    const float2* __restrict__ Sin,
    float* __restrict__ out)
{
    __shared__ float g_s[K * PITCH];
    __shared__ float u_s[K];

    const int g = blockIdx.x, h = blockIdx.y, n = threadIdx.x;
    const int hn = h * NBn + n;
    const int l0 = g * K;

    const float lre = Lre[hn], lim = Lim[hn];
    const float br  = Bre[hn], bi  = Bim[hn];
    const float cr  = Cre[hn], ci  = Cim[hn];
    const float Dh  = Dv[h];
    const float cbr2 = 2.f * (cr * br - ci * bi);   // 2*C*B
    const float cbi2 = 2.f * (cr * bi + ci * br);

    const float2 win = Sin[(h * G + g) * NBn + n];  // true incoming w
    const float ul = u[h * Ln + l0 + n];
    u_s[n] = ul;
    const unsigned long long m = __ballot(dflag[l0 + n] != 0);
    __syncthreads();

    float wr = win.x, wi = win.y;
    if (m == 0ull) {
        #pragma unroll
        for (int k = 0; k < K; ++k) {
            const float uk = u_s[k];
            const float nr = fmaf(lre, wr, fmaf(-lim, wi, cbr2 * uk));
            const float ni = fmaf(lre, wi, fmaf( lim, wr, cbi2 * uk));
            wr = nr; wi = ni;
            g_s[k * PITCH + n] = wr;               // only Re needed for y
        }
    } else {
        #pragma unroll
        for (int k = 0; k < K; ++k) {
            const bool  rs  = (m >> k) & 1ull;
            const float lrk = rs ? 0.f : lre;
            const float lik = rs ? 0.f : lim;
            const float uk  = u_s[k];
            const float nr = fmaf(lrk, wr, fmaf(-lik, wi, cbr2 * uk));
            const float ni = fmaf(lrk, wi, fmaf( lik, wr, cbi2 * uk));
            wr = nr; wi = ni;
            g_s[k * PITCH + n] = wr;
        }
    }
    __syncthreads();

    // lane t sums row t (timestep l0+t): conflict-free b32 at PITCH 65
    const float* row = g_s + n * PITCH;
    float a0 = 0.f, a1 = 0.f, a2 = 0.f, a3 = 0.f;
    #pragma unroll
    for (int k = 0; k < NBn; k += 4) {
        a0 += row[k + 0]; a1 += row[k + 1];
        a2 += row[k + 2]; a3 += row[k + 3];
    }
    out[h * Ln + l0 + n] = (a0 + a1) + (a2 + a3) + Dh * ul;
}

extern "C" void kernel_launch(void* const* d_in, const int* in_sizes, int n_in,
                              void* d_out, int out_size, void* d_ws, size_t ws_size,
                              hipStream_t stream) {
    const float* u    = (const float*)d_in[0];
    const float* x_re = (const float*)d_in[1];
    const float* x_im = (const float*)d_in[2];
    const float* Lre  = (const float*)d_in[3];
    const float* Lim  = (const float*)d_in[4];
    const float* Bre  = (const float*)d_in[5];
    const float* Bim  = (const float*)d_in[6];
    const float* Cre  = (const float*)d_in[7];
    const float* Cim  = (const float*)d_in[8];
    const float* Dv   = (const float*)d_in[9];
    const int*   dfl  = (const int*)d_in[10];
    float* out = (float*)d_out;

    float2* Sin = (float2*)d_ws;           // 2 MB

    kA_sum_combine<<<Hn, 1024, 0, stream>>>(u, x_re, x_im, Lre, Lim,
                                            Bre, Bim, Cre, Cim, dfl,
                                            Sin, out);
    dim3 gridB(G, Hn);
    kB_rescan<<<gridB, 64, 0, stream>>>(u, Lre, Lim, Bre, Bim, Cre, Cim,
                                        Dv, dfl, Sin, out);
}